// Round 3
// baseline (1938.686 us; speedup 1.0000x reference)
//
#include <hip/hip_runtime.h>
#include <hip/hip_bf16.h>
#include <stdint.h>

// Problem constants
#define NQ    2304          // H*W = 48*48 tokens
#define MROWS 4608          // B*NQ
#define DIMC  768
#define NHEAD 12
#define HEADS 24            // B*NH
#define HD    64

typedef unsigned int uint;
typedef unsigned short u16;

static __device__ __forceinline__ float bfbits2f(uint u) {
  union { uint i; float f; } c; c.i = u << 16; return c.f;
}

static __device__ __forceinline__ u16 f2bf(float f) {
  __hip_bfloat16 h = __float2bfloat16(f);
  union { __hip_bfloat16 h; u16 u; } c; c.h = h; return c.u;
}

static __device__ __forceinline__ void dec8(uint4 p, float* f) {
  f[0] = bfbits2f(p.x & 0xFFFFu); f[1] = bfbits2f(p.x >> 16);
  f[2] = bfbits2f(p.y & 0xFFFFu); f[3] = bfbits2f(p.y >> 16);
  f[4] = bfbits2f(p.z & 0xFFFFu); f[5] = bfbits2f(p.z >> 16);
  f[6] = bfbits2f(p.w & 0xFFFFu); f[7] = bfbits2f(p.w >> 16);
}

// Load 8 consecutive input elements starting at element index idx (idx % 8 == 0).
// bf==1: input is bf16 (u16). bf==0: input is fp32.
static __device__ __forceinline__ void ld8(const void* p, size_t idx, int bf, float* f) {
  if (bf) {
    uint4 v = *(const uint4*)((const u16*)p + idx);
    dec8(v, f);
  } else {
    const float4* q = (const float4*)((const float*)p + idx);
    float4 a = q[0], b = q[1];
    f[0] = a.x; f[1] = a.y; f[2] = a.z; f[3] = a.w;
    f[4] = b.x; f[5] = b.y; f[6] = b.z; f[7] = b.w;
  }
}

static __device__ __forceinline__ float ld1(const void* p, size_t idx, int bf) {
  return bf ? bfbits2f(((const u16*)p)[idx]) : ((const float*)p)[idx];
}

// ---------------------------------------------------------------------------
// K0: dtype detector.  x ~ N(0,1), >=3.5M elements, buffer >= 7 MB under
// either dtype, so reading 4096 u16s (8 KB) is always in-bounds.
// Even-indexed u16s: for bf16 data they are genuine bf16 normals (exponent
// field ~[113,133] essentially always); for fp32 data they are low mantissa
// halves (uniform exponent field, ~8% in range).  mode=1 -> bf16, 0 -> fp32.
// ---------------------------------------------------------------------------
__global__ __launch_bounds__(64) void detect_k(const u16* __restrict__ x,
                                               int* __restrict__ mode) {
  int t = threadIdx.x;
  int cnt = 0;
  for (int i = 0; i < 32; ++i) {
    uint u = x[(size_t)(t * 32 + i) * 2];   // even indices 0..4094
    uint e = (u >> 7) & 0xFFu;
    uint mag = u & 0x7FFFu;
    if (mag == 0 || (e >= 113 && e <= 133)) cnt++;
  }
#pragma unroll
  for (int d = 1; d < 64; d <<= 1) cnt += __shfl_xor(cnt, d);
  if (t == 0) mode[0] = (cnt > 1024) ? 1 : 0;   // of 2048 samples
}

// ---------------------------------------------------------------------------
// K1: QKV projection.  C[m][col] = sum_k X[m][k] * W[col][k] + b[col]
// X: (4608, 768), W: (2304, 768), dual dtype.  Output scattered (bf16) into
// Q/K/V laid out (B*NH, NQ, HD).  fp32 accumulate in-register.
// ---------------------------------------------------------------------------
__global__ __launch_bounds__(256) void qkv_gemm_k(
    const void* __restrict__ X, const void* __restrict__ W,
    const void* __restrict__ Bq, const int* __restrict__ mode,
    u16* __restrict__ Q, u16* __restrict__ K, u16* __restrict__ V)
{
  __shared__ float As[64][33];   // +1 pad: breaks stride-32 bank conflicts
  __shared__ float Bs[64][33];
  const int bf = mode[0];
  const int tid = threadIdx.x;
  const int tx = tid & 15, ty = tid >> 4;
  const int row0 = blockIdx.y << 6, col0 = blockIdx.x << 6;
  const int lr = tid >> 2, lk = (tid & 3) << 3;
  float acc[4][4] = {};

  for (int kt = 0; kt < DIMC; kt += 32) {
    float fa[8], fb[8];
    ld8(X, (size_t)(row0 + lr) * DIMC + kt + lk, bf, fa);
    ld8(W, (size_t)(col0 + lr) * DIMC + kt + lk, bf, fb);
#pragma unroll
    for (int j = 0; j < 8; ++j) { As[lr][lk + j] = fa[j]; Bs[lr][lk + j] = fb[j]; }
    __syncthreads();
#pragma unroll
    for (int kk = 0; kk < 32; ++kk) {
      float a[4], b[4];
#pragma unroll
      for (int i = 0; i < 4; ++i) a[i] = As[ty * 4 + i][kk];
#pragma unroll
      for (int j = 0; j < 4; ++j) b[j] = Bs[tx * 4 + j][kk];
#pragma unroll
      for (int i = 0; i < 4; ++i)
#pragma unroll
        for (int j = 0; j < 4; ++j) acc[i][j] += a[i] * b[j];
    }
    __syncthreads();
  }

#pragma unroll
  for (int j = 0; j < 4; ++j) {
    int col = col0 + tx * 4 + j;           // 0..2303
    int which = col / DIMC;                // 0=q 1=k 2=v
    int rem = col - which * DIMC;
    int head = rem >> 6, d = rem & 63;
    float bv = ld1(Bq, col, bf);
    u16* dst = (which == 0) ? Q : (which == 1) ? K : V;
#pragma unroll
    for (int i = 0; i < 4; ++i) {
      int mrow = row0 + ty * 4 + i;
      int b_ = mrow / NQ;
      int n = mrow - b_ * NQ;
      dst[(((size_t)(b_ * NHEAD + head)) * NQ + n) * HD + d] = f2bf(acc[i][j] + bv);
    }
  }
}

// ---------------------------------------------------------------------------
// K2: flash-style attention with fused decomposed rel-pos bias, per-head.
// Grid (72 q-tiles, 24 heads), 256 threads, QT=32 queries, KT=64 keys/tile.
// Thread t owns query row qi=t>>3; 8 lanes per row (same wave -> shfl ok).
// Q/K/V come from workspace (always bf16); rel tables dual-dtype.
// Output bf16 (b, n, head*64+d) into workspace for the proj GEMM.
// ---------------------------------------------------------------------------
#define QT 32
#define KT 64
__global__ __launch_bounds__(256) void attn_k(
    const u16* __restrict__ Q, const u16* __restrict__ K,
    const u16* __restrict__ V,
    const void* __restrict__ rph, const void* __restrict__ rpw,
    const int* __restrict__ mode,
    u16* __restrict__ Aout)
{
  __shared__ float Qs[QT][HD];        // UNSCALED q rows
  __shared__ float Ks[KT][HD + 1];
  __shared__ float Vs[KT][HD];
  __shared__ float Ss[QT][KT + 1];
  __shared__ float Bh[QT][48];
  __shared__ float Bw[QT][48];
  __shared__ int khs[KT];
  __shared__ int kws[KT];

  const int bf = mode[0];
  const int bh = blockIdx.y;
  const int q0 = blockIdx.x * QT;
  const int t = threadIdx.x;
  const int qi = t >> 3;
  const int l8 = (t & 7) << 3;
  const float scale = 0.125f;  // 64^-0.5

  // Q tile (unscaled) — thread loads 8 elements of its row
  {
    uint4 pq = *(const uint4*)(Q + ((size_t)bh * NQ + q0 + qi) * HD + l8);
    float fq[8]; dec8(pq, fq);
#pragma unroll
    for (int j = 0; j < 8; ++j) Qs[qi][l8 + j] = fq[j];
  }
  __syncthreads();   // Qs visible to all waves for bias compute

  // bias tiles: Bh[r][kh] = q_r . rel_pos_h[qh(r)-kh+47], Bw analogous
  for (int e = t; e < QT * 48; e += 256) {
    int r = e / 48, c = e - r * 48;
    int nq = q0 + r;
    int qh = nq / 48, qw = nq - qh * 48;
    size_t bh_idx = (size_t)(qh - c + 47) * HD;
    size_t bw_idx = (size_t)(qw - c + 47) * HD;
    float sh = 0.f, sw = 0.f;
#pragma unroll
    for (int v8 = 0; v8 < 8; ++v8) {
      float fh[8], fw[8];
      ld8(rph, bh_idx + v8 * 8, bf, fh);
      ld8(rpw, bw_idx + v8 * 8, bf, fw);
#pragma unroll
      for (int j = 0; j < 8; ++j) {
        float qv = Qs[r][v8 * 8 + j];
        sh += qv * fh[j];
        sw += qv * fw[j];
      }
    }
    Bh[r][c] = sh; Bw[r][c] = sw;
  }

  float m = -INFINITY, l = 0.f;
  float o[8];
#pragma unroll
  for (int dd = 0; dd < 8; ++dd) o[dd] = 0.f;

  const u16* kbase = K + (size_t)bh * NQ * HD;
  const u16* vbase = V + (size_t)bh * NQ * HD;

  for (int kt0 = 0; kt0 < NQ; kt0 += KT) {
    __syncthreads();   // bias done (iter 0) / prev-tile PV done
    {
      const uint4* gk = (const uint4*)(kbase + (size_t)kt0 * HD);
      const uint4* gv = (const uint4*)(vbase + (size_t)kt0 * HD);
#pragma unroll
      for (int i = 0; i < 2; ++i) {
        int c = t + i * 256;             // 0..511 chunks of 8 bf16
        int r = c >> 3, e8 = (c & 7) << 3;
        float fk[8], fv[8];
        dec8(gk[c], fk); dec8(gv[c], fv);
#pragma unroll
        for (int j = 0; j < 8; ++j) { Ks[r][e8 + j] = fk[j]; Vs[r][e8 + j] = fv[j]; }
      }
      if (t < KT) { int jg = kt0 + t; khs[t] = jg / 48; kws[t] = jg - (jg / 48) * 48; }
    }
    __syncthreads();

    // scores: thread computes 8 keys (l8..l8+7) for row qi
    float s[8];
#pragma unroll
    for (int jj = 0; jj < 8; ++jj) s[jj] = 0.f;
#pragma unroll 8
    for (int kk = 0; kk < HD; ++kk) {
      float qv = Qs[qi][kk];
#pragma unroll
      for (int jj = 0; jj < 8; ++jj) s[jj] += qv * Ks[l8 + jj][kk];
    }
#pragma unroll
    for (int jj = 0; jj < 8; ++jj) {
      int j = l8 + jj;
      s[jj] = s[jj] * scale + Bh[qi][khs[j]] + Bw[qi][kws[j]];
    }

    // online softmax (8 lanes of a query row are contiguous in one wave)
    float mx = s[0];
#pragma unroll
    for (int jj = 1; jj < 8; ++jj) mx = fmaxf(mx, s[jj]);
    mx = fmaxf(mx, __shfl_xor(mx, 1));
    mx = fmaxf(mx, __shfl_xor(mx, 2));
    mx = fmaxf(mx, __shfl_xor(mx, 4));
    float m_new = fmaxf(m, mx);
    float alpha = __expf(m - m_new);
    float sum = 0.f;
#pragma unroll
    for (int jj = 0; jj < 8; ++jj) {
      float p = __expf(s[jj] - m_new);
      Ss[qi][l8 + jj] = p;
      sum += p;
    }
    sum += __shfl_xor(sum, 1);
    sum += __shfl_xor(sum, 2);
    sum += __shfl_xor(sum, 4);
    l = l * alpha + sum;
    m = m_new;
#pragma unroll
    for (int dd = 0; dd < 8; ++dd) o[dd] *= alpha;

    // PV: o[d] += sum_j P[qi][j] * V[j][d]  (reads only own wave's Ss rows)
#pragma unroll 4
    for (int j = 0; j < KT; ++j) {
      float p = Ss[qi][j];
      const float* vr = &Vs[j][l8];
#pragma unroll
      for (int dd = 0; dd < 8; ++dd) o[dd] += p * vr[dd];
    }
  }

  float inv = 1.f / l;
  int b_ = bh / NHEAD, head = bh - b_ * NHEAD;
  u16* dst = Aout + ((size_t)b_ * NQ + q0 + qi) * DIMC + head * HD + l8;
#pragma unroll
  for (int dd = 0; dd < 8; ++dd) dst[dd] = f2bf(o[dd] * inv);
}

// ---------------------------------------------------------------------------
// K3: output projection.  Out[m][col] = sum_k A[m][k]*W[col][k] + b[col]
// A: (4608,768) bf16 (workspace), W: (768,768) dual-dtype, Out dual-dtype.
// ---------------------------------------------------------------------------
__global__ __launch_bounds__(256) void proj_gemm_k(
    const u16* __restrict__ A, const void* __restrict__ W,
    const void* __restrict__ Bp, const int* __restrict__ mode,
    void* __restrict__ Out)
{
  __shared__ float As[64][33];
  __shared__ float Bs[64][33];
  const int bf = mode[0];
  const int tid = threadIdx.x;
  const int tx = tid & 15, ty = tid >> 4;
  const int row0 = blockIdx.y << 6, col0 = blockIdx.x << 6;
  const int lr = tid >> 2, lk = (tid & 3) << 3;
  float acc[4][4] = {};

  for (int kt = 0; kt < DIMC; kt += 32) {
    uint4 pa = *(const uint4*)(A + (size_t)(row0 + lr) * DIMC + kt + lk);
    float fa[8], fb[8];
    dec8(pa, fa);
    ld8(W, (size_t)(col0 + lr) * DIMC + kt + lk, bf, fb);
#pragma unroll
    for (int j = 0; j < 8; ++j) { As[lr][lk + j] = fa[j]; Bs[lr][lk + j] = fb[j]; }
    __syncthreads();
#pragma unroll
    for (int kk = 0; kk < 32; ++kk) {
      float a[4], b[4];
#pragma unroll
      for (int i = 0; i < 4; ++i) a[i] = As[ty * 4 + i][kk];
#pragma unroll
      for (int j = 0; j < 4; ++j) b[j] = Bs[tx * 4 + j][kk];
#pragma unroll
      for (int i = 0; i < 4; ++i)
#pragma unroll
        for (int j = 0; j < 4; ++j) acc[i][j] += a[i] * b[j];
    }
    __syncthreads();
  }

#pragma unroll
  for (int j = 0; j < 4; ++j) {
    int col = col0 + tx * 4 + j;
    float bv = ld1(Bp, col, bf);
#pragma unroll
    for (int i = 0; i < 4; ++i) {
      int mrow = row0 + ty * 4 + i;
      float val = acc[i][j] + bv;
      size_t off = (size_t)mrow * DIMC + col;
      if (bf) ((u16*)Out)[off] = f2bf(val);
      else    ((float*)Out)[off] = val;
    }
  }
}

// ---------------------------------------------------------------------------
extern "C" void kernel_launch(void* const* d_in, const int* in_sizes, int n_in,
                              void* d_out, int out_size, void* d_ws, size_t ws_size,
                              hipStream_t stream)
{
  const void* x    = d_in[0];   // (2,48,48,768)
  const void* rph  = d_in[1];   // (95,64)
  const void* rpw  = d_in[2];   // (95,64)
  const void* qkvw = d_in[3];   // (2304,768)
  const void* qkvb = d_in[4];   // (2304,)
  const void* pw   = d_in[5];   // (768,768)
  const void* pb   = d_in[6];   // (768,)

  // Workspace: [mode flag 16B] q,k,v bf16 (24,2304,64); aout bf16 (2,2304,768).
  // Total ~28.3 MB.
  int* mode = (int*)d_ws;
  const size_t qkv_elems = (size_t)HEADS * NQ * HD;   // 3,538,944
  u16* q    = (u16*)((char*)d_ws + 16);
  u16* k    = q + qkv_elems;
  u16* v    = k + qkv_elems;
  u16* aout = v + qkv_elems;

  detect_k<<<1, 64, 0, stream>>>((const u16*)x, mode);
  qkv_gemm_k<<<dim3(36, 72), 256, 0, stream>>>(x, qkvw, qkvb, mode, q, k, v);
  attn_k<<<dim3(NQ / QT, HEADS), 256, 0, stream>>>(q, k, v, rph, rpw, mode, aout);
  proj_gemm_k<<<dim3(12, 72), 256, 0, stream>>>(aout, pw, pb, mode, d_out);
}

// Round 4
// 553.561 us; speedup vs baseline: 3.5022x; 3.5022x over previous
//
#include <hip/hip_runtime.h>
#include <hip/hip_bf16.h>
#include <stdint.h>

// Problem constants
#define NQ    2304          // H*W = 48*48 tokens
#define MROWS 4608          // B*NQ
#define DIMC  768
#define NHEAD 12
#define HEADS 24            // B*NH
#define HD    64

typedef unsigned int uint;
typedef unsigned short u16;
typedef __attribute__((ext_vector_type(8))) short s16x8;   // 8 bf16 = 4 VGPR
typedef __attribute__((ext_vector_type(4))) float f32x4;   // mfma acc

#define MFMA16(a, b, c) __builtin_amdgcn_mfma_f32_16x16x32_bf16((a), (b), (c), 0, 0, 0)

static __device__ __forceinline__ float bfbits2f(uint u) {
  union { uint i; float f; } c; c.i = u << 16; return c.f;
}
static __device__ __forceinline__ u16 f2bf(float f) {
  __hip_bfloat16 h = __float2bfloat16(f);
  union { __hip_bfloat16 h; u16 u; } c; c.h = h; return c.u;
}
static __device__ __forceinline__ void dec8(uint4 p, float* f) {
  f[0] = bfbits2f(p.x & 0xFFFFu); f[1] = bfbits2f(p.x >> 16);
  f[2] = bfbits2f(p.y & 0xFFFFu); f[3] = bfbits2f(p.y >> 16);
  f[4] = bfbits2f(p.z & 0xFFFFu); f[5] = bfbits2f(p.z >> 16);
  f[6] = bfbits2f(p.w & 0xFFFFu); f[7] = bfbits2f(p.w >> 16);
}
// dual-dtype 8-element load -> fp32 (bf=1: bf16, bf=0: fp32)
static __device__ __forceinline__ void ld8(const void* p, size_t idx, int bf, float* f) {
  if (bf) { dec8(*(const uint4*)((const u16*)p + idx), f); }
  else {
    const float4* q = (const float4*)((const float*)p + idx);
    float4 a = q[0], b = q[1];
    f[0] = a.x; f[1] = a.y; f[2] = a.z; f[3] = a.w;
    f[4] = b.x; f[5] = b.y; f[6] = b.z; f[7] = b.w;
  }
}
static __device__ __forceinline__ float ld1(const void* p, size_t idx, int bf) {
  return bf ? bfbits2f(((const u16*)p)[idx]) : ((const float*)p)[idx];
}
// dual-dtype 8-element load -> packed bf16 (uint4)
static __device__ __forceinline__ uint4 ld8_to_bf(const void* p, size_t idx, int bf) {
  if (bf) return *(const uint4*)((const u16*)p + idx);
  float f[8]; ld8(p, idx, 0, f);
  uint4 u;
  u.x = (uint)f2bf(f[0]) | ((uint)f2bf(f[1]) << 16);
  u.y = (uint)f2bf(f[2]) | ((uint)f2bf(f[3]) << 16);
  u.z = (uint)f2bf(f[4]) | ((uint)f2bf(f[5]) << 16);
  u.w = (uint)f2bf(f[6]) | ((uint)f2bf(f[7]) << 16);
  return u;
}

// ---------------------------------------------------------------------------
// K0: dtype detector (unchanged from round 3 — PASSED; do not touch).
// ---------------------------------------------------------------------------
__global__ __launch_bounds__(64) void detect_k(const u16* __restrict__ x,
                                               int* __restrict__ mode) {
  int t = threadIdx.x;
  int cnt = 0;
  for (int i = 0; i < 32; ++i) {
    uint u = x[(size_t)(t * 32 + i) * 2];
    uint e = (u >> 7) & 0xFFu;
    uint mag = u & 0x7FFFu;
    if (mag == 0 || (e >= 113 && e <= 133)) cnt++;
  }
#pragma unroll
  for (int d = 1; d < 64; d <<= 1) cnt += __shfl_xor(cnt, d);
  if (t == 0) mode[0] = (cnt > 1024) ? 1 : 0;
}

// ---------------------------------------------------------------------------
// K1: QKV projection, MFMA.  C[m][col] = sum_k X[m][k]*W[col][k] + b[col].
// 128x128 tile, BK=32, 4 waves each 64x64 (4x4 grid of 16x16x32 mfma).
// Output scattered bf16 into Q/K/V (B*NH, NQ, HD).
// ---------------------------------------------------------------------------
__global__ __launch_bounds__(256) void qkv_gemm_k(
    const void* __restrict__ Xp, const void* __restrict__ Wp,
    const void* __restrict__ Bq, const int* __restrict__ mode,
    u16* __restrict__ Q, u16* __restrict__ K, u16* __restrict__ V)
{
  __shared__ __align__(16) u16 As[128][40];   // stride 40 bf16 = 80 B (16B-aligned rows)
  __shared__ __align__(16) u16 Bs[128][40];
  const int bf = mode[0];
  const int t = threadIdx.x;
  const int w = t >> 6, l15 = t & 15, quad = (t >> 4) & 3;
  const int wr = w >> 1, wc = w & 1;
  const int row0 = blockIdx.y << 7, col0 = blockIdx.x << 7;
  const int lr = t >> 1, lk = (t & 1) << 4;

  f32x4 zero4 = {0.f, 0.f, 0.f, 0.f};
  f32x4 acc[4][4];
#pragma unroll
  for (int i = 0; i < 4; ++i)
#pragma unroll
    for (int j = 0; j < 4; ++j) acc[i][j] = zero4;

  for (int kt = 0; kt < DIMC; kt += 32) {
    __syncthreads();
    *(uint4*)&As[lr][lk]     = ld8_to_bf(Xp, (size_t)(row0 + lr) * DIMC + kt + lk, bf);
    *(uint4*)&As[lr][lk + 8] = ld8_to_bf(Xp, (size_t)(row0 + lr) * DIMC + kt + lk + 8, bf);
    *(uint4*)&Bs[lr][lk]     = ld8_to_bf(Wp, (size_t)(col0 + lr) * DIMC + kt + lk, bf);
    *(uint4*)&Bs[lr][lk + 8] = ld8_to_bf(Wp, (size_t)(col0 + lr) * DIMC + kt + lk + 8, bf);
    __syncthreads();
    s16x8 af[4], bfr[4];
#pragma unroll
    for (int i = 0; i < 4; ++i)
      af[i] = *(const s16x8*)&As[(wr << 6) + (i << 4) + l15][quad << 3];
#pragma unroll
    for (int j = 0; j < 4; ++j)
      bfr[j] = *(const s16x8*)&Bs[(wc << 6) + (j << 4) + l15][quad << 3];
#pragma unroll
    for (int i = 0; i < 4; ++i)
#pragma unroll
      for (int j = 0; j < 4; ++j)
        acc[i][j] = MFMA16(af[i], bfr[j], acc[i][j]);
  }

#pragma unroll
  for (int jt = 0; jt < 4; ++jt) {
    int col = col0 + (wc << 6) + (jt << 4) + l15;     // 0..2303
    int which = col / DIMC;
    int rem = col - which * DIMC;
    int head = rem >> 6, d = rem & 63;
    float bv = ld1(Bq, col, bf);
    u16* dst = (which == 0) ? Q : (which == 1) ? K : V;
#pragma unroll
    for (int i = 0; i < 4; ++i)
#pragma unroll
      for (int r = 0; r < 4; ++r) {
        int mrow = row0 + (wr << 6) + (i << 4) + (quad << 2) + r;
        int b_ = (mrow >= NQ) ? 1 : 0;
        int n = mrow - b_ * NQ;
        dst[(((size_t)(b_ * NHEAD + head)) * NQ + n) * HD + d] = f2bf(acc[i][jt][r] + bv);
      }
  }
}

// ---------------------------------------------------------------------------
// K2: MFMA flash attention with fused decomposed rel-pos bias.
// Block = (64 q-rows, 1 head); 4 waves, wave w owns rows w*16..w*16+15.
// Q A-frags in registers (loop-invariant). KT=64 keys/tile.
// P relayout C->A via wave-private LDS round-trip (lgkmcnt(0) guarded).
// ---------------------------------------------------------------------------
__global__ __launch_bounds__(256) void attn_k(
    const u16* __restrict__ Qw, const u16* __restrict__ Kw,
    const u16* __restrict__ Vw,
    const void* __restrict__ rph, const void* __restrict__ rpw,
    const int* __restrict__ mode,
    u16* __restrict__ Aout)
{
  __shared__ __align__(16) u16 Ks[64][72];        // [key][kdim]
  __shared__ __align__(16) u16 Vt[64][72];        // [d][key]  (V transposed)
  __shared__ __align__(16) u16 Ps[4][16][72];     // per-wave P round-trip
  __shared__ float Bh[64][49];                    // [local qrow][kh]
  __shared__ float Bw[64][49];                    // [local qrow][kw]

  const int bf = mode[0];
  const int bh = blockIdx.y;
  const int q0 = blockIdx.x << 6;
  const int t = threadIdx.x;
  const int w = t >> 6, l15 = t & 15, quad = (t >> 4) & 3;
  const float scale = 0.125f;   // 64^-0.5

  // Q A-frags: A[m=l15][k=quad*8+j], ksteps 0/1
  const u16* qfrag = Qw + ((size_t)bh * NQ + q0 + (w << 4) + l15) * HD + (quad << 3);
  s16x8 qa0 = *(const s16x8*)(qfrag);
  s16x8 qa1 = *(const s16x8*)(qfrag + 32);

  // Bias tiles (scalar, once per block): Bh[r][c] = q_row . rel_h[qh-c+47]
  for (int e = t; e < 64 * 48; e += 256) {
    int r = (e * 10923) >> 19;          // e/48
    int c = e - r * 48;
    int n = q0 + r;
    int qh = (n * 10923) >> 19;         // n/48
    int qw_ = n - qh * 48;
    const u16* qr = Qw + ((size_t)bh * NQ + n) * HD;
    size_t ih = (size_t)(qh - c + 47) * HD;
    size_t iw = (size_t)(qw_ - c + 47) * HD;
    float sh = 0.f, sw = 0.f;
#pragma unroll
    for (int v8 = 0; v8 < 8; ++v8) {
      float fq[8], fh[8], fw[8];
      dec8(*(const uint4*)(qr + (v8 << 3)), fq);
      ld8(rph, ih + (v8 << 3), bf, fh);
      ld8(rpw, iw + (v8 << 3), bf, fw);
#pragma unroll
      for (int j = 0; j < 8; ++j) { sh += fq[j] * fh[j]; sw += fq[j] * fw[j]; }
    }
    Bh[r][c] = sh; Bw[r][c] = sw;
  }

  f32x4 zero4 = {0.f, 0.f, 0.f, 0.f};
  f32x4 acc_o[4];
#pragma unroll
  for (int nc = 0; nc < 4; ++nc) acc_o[nc] = zero4;
  float m_st[4] = {-INFINITY, -INFINITY, -INFINITY, -INFINITY};
  float l_st[4] = {0.f, 0.f, 0.f, 0.f};

  const u16* kbase = Kw + (size_t)bh * NQ * HD;
  const u16* vbase = Vw + (size_t)bh * NQ * HD;

  for (int kt0 = 0; kt0 < NQ; kt0 += 64) {
    __syncthreads();   // prev-tile reads done (also fences bias writes on iter 0)
    // stage K (raw bf16 copy) and V (transposed, bank-rotated b16 writes)
    {
      int rot = t & 7;
#pragma unroll
      for (int i = 0; i < 2; ++i) {
        int c = t + (i << 8);                 // 0..511
        int key = c >> 3, col8 = (c & 7) << 3;
        *(uint4*)&Ks[key][col8] = *(const uint4*)(kbase + (size_t)(kt0 + key) * HD + col8);
        uint4 pv = *(const uint4*)(vbase + (size_t)(kt0 + key) * HD + col8);
        u16 vals[8];
        vals[0] = pv.x & 0xFFFFu; vals[1] = pv.x >> 16;
        vals[2] = pv.y & 0xFFFFu; vals[3] = pv.y >> 16;
        vals[4] = pv.z & 0xFFFFu; vals[5] = pv.z >> 16;
        vals[6] = pv.w & 0xFFFFu; vals[7] = pv.w >> 16;
#pragma unroll
        for (int jj = 0; jj < 8; ++jj) {
          int j = (jj + rot) & 7;
          Vt[col8 + j][key] = vals[j];
        }
      }
    }
    __syncthreads();

    // S = Q K^T : 8 mfma -> acc_s[nc] (C layout: row=quad*4+reg, col=l15)
    f32x4 acc_s[4];
#pragma unroll
    for (int nc = 0; nc < 4; ++nc) {
      s16x8 kb0 = *(const s16x8*)&Ks[(nc << 4) + l15][quad << 3];
      s16x8 kb1 = *(const s16x8*)&Ks[(nc << 4) + l15][32 + (quad << 3)];
      f32x4 a = MFMA16(qa0, kb0, zero4);
      acc_s[nc] = MFMA16(qa1, kb1, a);
    }

    // scale + rel-pos bias
    int khv[4], kwv[4];
#pragma unroll
    for (int nc = 0; nc < 4; ++nc) {
      int key = kt0 + (nc << 4) + l15;
      int kh = (key * 10923) >> 19;
      khv[nc] = kh; kwv[nc] = key - kh * 48;
    }
    float sv[4][4];
#pragma unroll
    for (int nc = 0; nc < 4; ++nc)
#pragma unroll
      for (int r = 0; r < 4; ++r) {
        int rowl = (w << 4) + (quad << 2) + r;
        sv[nc][r] = acc_s[nc][r] * scale + Bh[rowl][khv[nc]] + Bw[rowl][kwv[nc]];
      }

    // online softmax per row r (16-lane quad reduction)
#pragma unroll
    for (int r = 0; r < 4; ++r) {
      float mx = fmaxf(fmaxf(sv[0][r], sv[1][r]), fmaxf(sv[2][r], sv[3][r]));
      mx = fmaxf(mx, __shfl_xor(mx, 1));
      mx = fmaxf(mx, __shfl_xor(mx, 2));
      mx = fmaxf(mx, __shfl_xor(mx, 4));
      mx = fmaxf(mx, __shfl_xor(mx, 8));
      float mn = fmaxf(m_st[r], mx);
      float al = __expf(m_st[r] - mn);
      float sum = 0.f;
#pragma unroll
      for (int nc = 0; nc < 4; ++nc) {
        float p = __expf(sv[nc][r] - mn);
        Ps[w][(quad << 2) + r][(nc << 4) + l15] = f2bf(p);
        sum += p;
      }
      sum += __shfl_xor(sum, 1);
      sum += __shfl_xor(sum, 2);
      sum += __shfl_xor(sum, 4);
      sum += __shfl_xor(sum, 8);
      l_st[r] = l_st[r] * al + sum;
      m_st[r] = mn;
#pragma unroll
      for (int nc = 0; nc < 4; ++nc) acc_o[nc][r] = acc_o[nc][r] * al;
    }

    // drain LDS writes: cross-lane P round-trip within the wave
    __builtin_amdgcn_s_waitcnt(0xC07F);   // lgkmcnt(0), vmcnt/expcnt untouched

    // O += P V : P A-frags from own-wave Ps, V B-frags from Vt
    s16x8 pf0 = *(const s16x8*)&Ps[w][l15][quad << 3];
    s16x8 pf1 = *(const s16x8*)&Ps[w][l15][32 + (quad << 3)];
#pragma unroll
    for (int nc = 0; nc < 4; ++nc) {
      s16x8 vb0 = *(const s16x8*)&Vt[(nc << 4) + l15][quad << 3];
      s16x8 vb1 = *(const s16x8*)&Vt[(nc << 4) + l15][32 + (quad << 3)];
      acc_o[nc] = MFMA16(pf0, vb0, acc_o[nc]);
      acc_o[nc] = MFMA16(pf1, vb1, acc_o[nc]);
    }
  }

  // epilogue: divide by l, store bf16 to (b, token, head*64+d)
  int b_ = bh / NHEAD, head = bh - b_ * NHEAD;
#pragma unroll
  for (int r = 0; r < 4; ++r) {
    float inv = 1.f / l_st[r];
    int token = q0 + (w << 4) + (quad << 2) + r;
    u16* dst = Aout + ((size_t)b_ * NQ + token) * DIMC + (head << 6);
#pragma unroll
    for (int nc = 0; nc < 4; ++nc)
      dst[(nc << 4) + l15] = f2bf(acc_o[nc][r] * inv);
  }
}

// ---------------------------------------------------------------------------
// K3: output projection, MFMA.  Out[m][col] = sum_k A[m][k]*W[col][k] + b[col]
// A: (4608,768) bf16 workspace (raw staging), W dual-dtype, Out dual-dtype.
// ---------------------------------------------------------------------------
__global__ __launch_bounds__(256) void proj_gemm_k(
    const u16* __restrict__ A, const void* __restrict__ Wp,
    const void* __restrict__ Bp, const int* __restrict__ mode,
    void* __restrict__ Out)
{
  __shared__ __align__(16) u16 As[128][40];
  __shared__ __align__(16) u16 Bs[128][40];
  const int bf = mode[0];
  const int t = threadIdx.x;
  const int w = t >> 6, l15 = t & 15, quad = (t >> 4) & 3;
  const int wr = w >> 1, wc = w & 1;
  const int row0 = blockIdx.y << 7, col0 = blockIdx.x << 7;
  const int lr = t >> 1, lk = (t & 1) << 4;

  f32x4 zero4 = {0.f, 0.f, 0.f, 0.f};
  f32x4 acc[4][4];
#pragma unroll
  for (int i = 0; i < 4; ++i)
#pragma unroll
    for (int j = 0; j < 4; ++j) acc[i][j] = zero4;

  for (int kt = 0; kt < DIMC; kt += 32) {
    __syncthreads();
    *(uint4*)&As[lr][lk]     = *(const uint4*)(A + (size_t)(row0 + lr) * DIMC + kt + lk);
    *(uint4*)&As[lr][lk + 8] = *(const uint4*)(A + (size_t)(row0 + lr) * DIMC + kt + lk + 8);
    *(uint4*)&Bs[lr][lk]     = ld8_to_bf(Wp, (size_t)(col0 + lr) * DIMC + kt + lk, bf);
    *(uint4*)&Bs[lr][lk + 8] = ld8_to_bf(Wp, (size_t)(col0 + lr) * DIMC + kt + lk + 8, bf);
    __syncthreads();
    s16x8 af[4], bfr[4];
#pragma unroll
    for (int i = 0; i < 4; ++i)
      af[i] = *(const s16x8*)&As[(wr << 6) + (i << 4) + l15][quad << 3];
#pragma unroll
    for (int j = 0; j < 4; ++j)
      bfr[j] = *(const s16x8*)&Bs[(wc << 6) + (j << 4) + l15][quad << 3];
#pragma unroll
    for (int i = 0; i < 4; ++i)
#pragma unroll
      for (int j = 0; j < 4; ++j)
        acc[i][j] = MFMA16(af[i], bfr[j], acc[i][j]);
  }

#pragma unroll
  for (int jt = 0; jt < 4; ++jt) {
    int col = col0 + (wc << 6) + (jt << 4) + l15;
    float bv = ld1(Bp, col, bf);
#pragma unroll
    for (int i = 0; i < 4; ++i)
#pragma unroll
      for (int r = 0; r < 4; ++r) {
        int mrow = row0 + (wr << 6) + (i << 4) + (quad << 2) + r;
        float val = acc[i][jt][r] + bv;
        size_t off = (size_t)mrow * DIMC + col;
        if (bf) ((u16*)Out)[off] = f2bf(val);
        else    ((float*)Out)[off] = val;
      }
  }
}

// ---------------------------------------------------------------------------
extern "C" void kernel_launch(void* const* d_in, const int* in_sizes, int n_in,
                              void* d_out, int out_size, void* d_ws, size_t ws_size,
                              hipStream_t stream)
{
  const void* x    = d_in[0];   // (2,48,48,768)
  const void* rph  = d_in[1];   // (95,64)
  const void* rpw  = d_in[2];   // (95,64)
  const void* qkvw = d_in[3];   // (2304,768)
  const void* qkvb = d_in[4];   // (2304,)
  const void* pw   = d_in[5];   // (768,768)
  const void* pb   = d_in[6];   // (768,)

  // Workspace: [mode 16B] q,k,v bf16 (24,2304,64); aout bf16 (2,2304,768). ~28.3 MB.
  int* mode = (int*)d_ws;
  const size_t qkv_elems = (size_t)HEADS * NQ * HD;   // 3,538,944
  u16* q    = (u16*)((char*)d_ws + 16);
  u16* k    = q + qkv_elems;
  u16* v    = k + qkv_elems;
  u16* aout = v + qkv_elems;

  detect_k<<<1, 64, 0, stream>>>((const u16*)x, mode);
  qkv_gemm_k<<<dim3(18, 36), 256, 0, stream>>>(x, qkvw, qkvb, mode, q, k, v);
  attn_k<<<dim3(NQ / 64, HEADS), 256, 0, stream>>>(q, k, v, rph, rpw, mode, aout);
  proj_gemm_k<<<dim3(6, 36), 256, 0, stream>>>(aout, pw, pb, mode, d_out);
}